// Round 8
// baseline (1230.134 us; speedup 1.0000x reference)
//
#include <hip/hip_runtime.h>
#include <hip/hip_bf16.h>
#include <math.h>

#define D 128
#define WS 136            // LDS row stride in shorts (staging tiles)
#define FS 132            // LDS row stride in floats (f32 out tile)
#define ALD 132           // LDS accumulator leading dim (floats)
#define PB 128            // partition blocks

typedef __attribute__((ext_vector_type(8))) short bf16x8;
typedef __attribute__((ext_vector_type(4))) float f32x4;
typedef __attribute__((ext_vector_type(2))) float f32x2;

__device__ __forceinline__ unsigned short f2bf(float f){
  return (unsigned short)((__float_as_uint(f) + 0x8000u) >> 16);
}
__device__ __forceinline__ float bf2f(unsigned short h){
  return __uint_as_float(((unsigned)h) << 16);
}
__device__ __forceinline__ float gelu_fast(float v){
  float u = v * v;
  float arg = v * (1.5957691216f + 0.0713548163f * u);
  arg = fminf(arg, 60.0f);
  float e = __expf(arg);
  return v * e * __builtin_amdgcn_rcpf(e + 1.0f);
}
// pack 8 f32 -> 8 fp8 e4m3 (OCP on gfx950), RNE in HW
__device__ __forceinline__ uint2 pack_fp8_8(const float* f){
  int a = __builtin_amdgcn_cvt_pk_fp8_f32(f[0], f[1], 0, false);
  a = __builtin_amdgcn_cvt_pk_fp8_f32(f[2], f[3], a, true);
  int b = __builtin_amdgcn_cvt_pk_fp8_f32(f[4], f[5], 0, false);
  b = __builtin_amdgcn_cvt_pk_fp8_f32(f[6], f[7], b, true);
  return make_uint2((unsigned)a, (unsigned)b);
}

// ---- fused: weight convert (blocks 0..47) + bucket count (blocks 48..48+PB)
//      buckets are now 64 nodes wide (edst >> 6) ----
__global__ __launch_bounds__(256) void k_prepcnt(const float* s0, const float* s1,
    const float* s2, const float* s3, const float* s4, const float* s5,
    unsigned short* dst, const int* __restrict__ edst, int* __restrict__ cnt,
    int E, int nbuck, int epb){
  __shared__ int hist[1024];
  if (blockIdx.x < 48){
    int gt = blockIdx.x * 256 + threadIdx.x;
    int m = gt >> 11;
    int r = gt & 2047;
    int f = r >> 6, lane = r & 63;
    int t = f & 7, kk = f >> 3;
    int row = t * 16 + (lane & 15);
    int col = kk * 32 + (lane >> 4) * 8;
    const float* src;
    if (m == 0) src = s0; else if (m == 1) src = s1; else if (m == 2) src = s2;
    else if (m == 3) src = s3; else if (m == 4) src = s4; else src = s5;
    src += row * 128 + col;
    float4 a = *(const float4*)src;
    float4 bb = *(const float4*)(src + 4);
    bf16x8 o;
    o[0] = (short)f2bf(a.x);  o[1] = (short)f2bf(a.y);
    o[2] = (short)f2bf(a.z);  o[3] = (short)f2bf(a.w);
    o[4] = (short)f2bf(bb.x); o[5] = (short)f2bf(bb.y);
    o[6] = (short)f2bf(bb.z); o[7] = (short)f2bf(bb.w);
    int pair = m >> 1, half = m & 1;
    *(bf16x8*)(dst + (size_t)pair * 32768 + (((size_t)f * 2 + half) * 64 + lane) * 8) = o;
    return;
  }
  int blk = blockIdx.x - 48;
  for (int b = threadIdx.x; b < nbuck; b += 256) hist[b] = 0;
  __syncthreads();
  int start = blk * epb;
  int end = min(E, start + epb);
  for (int e = start + threadIdx.x; e < end; e += 256)
    atomicAdd(&hist[edst[e] >> 6], 1);
  __syncthreads();
  for (int b = threadIdx.x; b < nbuck; b += 256) cnt[blk * nbuck + b] = hist[b];
}

// ---- per-bucket parallel scan over the PB partitions ----
__global__ __launch_bounds__(128) void k_scanA(const int* __restrict__ cnt,
    int* __restrict__ offs_rel, int* __restrict__ tot, int nbuck){
  __shared__ int sm[128];
  int b = blockIdx.x, t = threadIdx.x;
  int v = cnt[t * nbuck + b];
  sm[t] = v; __syncthreads();
  for (int ofs = 1; ofs < 128; ofs <<= 1){
    int u = (t >= ofs) ? sm[t - ofs] : 0;
    __syncthreads();
    sm[t] += u;
    __syncthreads();
  }
  offs_rel[t * nbuck + b] = sm[t] - v;
  if (t == 127) tot[b] = sm[127];
}

// ---- fused: bucket scatter (blocks < PB) + input layer GEMM (blocks >= PB) ----
__global__ __launch_bounds__(256) void k_pscatgemm(
    const int* __restrict__ esrc, const int* __restrict__ edst,
    const int* __restrict__ offs_rel, const int* __restrict__ tot,
    unsigned* __restrict__ ebuf,
    const float* __restrict__ x, const unsigned short* __restrict__ wp,
    const float* __restrict__ scb, const float* __restrict__ dpb,
    unsigned short* __restrict__ sbuf, unsigned short* __restrict__ hbuf,
    unsigned char* __restrict__ hb8,
    int N, int E, int nbuck, int epb){
  __shared__ char smem[64 * WS * 2];
  int tid = threadIdx.x;
  if ((int)blockIdx.x < PB){
    int* stot = (int*)smem;          // 1024 ints
    int* loff = stot + 1024;         // 1024 ints
    for (int b = tid; b < nbuck; b += 256) stot[b] = tot[b];
    __syncthreads();
    for (int b = tid; b < nbuck; b += 256){
      int s = 0;
      for (int j = 0; j < b; j++) s += stot[j];
      loff[b] = s + offs_rel[blockIdx.x * nbuck + b];
    }
    __syncthreads();
    int start = blockIdx.x * epb;
    int end = min(E, start + epb);
    for (int e = start + tid; e < end; e += 256){
      int s = esrc[e], d = edst[e];
      int pos = atomicAdd(&loff[d >> 6], 1);
      ebuf[pos] = (unsigned)s | ((unsigned)(d & 63) << 16);
    }
    return;
  }
  // ---- input GEMM part ----
  unsigned short* tile = (unsigned short*)smem;
  int bx = blockIdx.x - PB;
  int w = tid >> 6, lane = tid & 63, quad = lane >> 4, l16 = lane & 15;
  int nbb = bx * 64;
  int nb = nbb + w * 16;
  int arow = min(nb + l16, N - 1);
  f32x4 acc[2][8];
  #pragma unroll
  for (int m = 0; m < 2; m++)
    #pragma unroll
    for (int t = 0; t < 8; t++) acc[m][t] = (f32x4){0.f, 0.f, 0.f, 0.f};
  #pragma unroll
  for (int kk = 0; kk < 4; kk++){
    const float* xp = x + (size_t)arow * D + kk * 32 + quad * 8;
    float4 xa = *(const float4*)xp;
    float4 xb = *(const float4*)(xp + 4);
    bf16x8 a;
    a[0] = (short)f2bf(xa.x); a[1] = (short)f2bf(xa.y);
    a[2] = (short)f2bf(xa.z); a[3] = (short)f2bf(xa.w);
    a[4] = (short)f2bf(xb.x); a[5] = (short)f2bf(xb.y);
    a[6] = (short)f2bf(xb.z); a[7] = (short)f2bf(xb.w);
    #pragma unroll
    for (int t = 0; t < 8; t++){
      size_t fo = (((size_t)(kk * 8 + t) * 2) * 64 + lane) * 8;
      bf16x8 b0 = *(const bf16x8*)(wp + fo);
      bf16x8 b1 = *(const bf16x8*)(wp + fo + 512);
      acc[0][t] = __builtin_amdgcn_mfma_f32_16x16x32_bf16(a, b0, acc[0][t], 0, 0, 0);
      acc[1][t] = __builtin_amdgcn_mfma_f32_16x16x32_bf16(a, b1, acc[1][t], 0, 0, 0);
    }
  }
  #pragma unroll
  for (int m = 0; m < 2; m++){
    const float* bias = m ? dpb : scb;
    #pragma unroll
    for (int t = 0; t < 8; t++){
      float bv = bias[t * 16 + l16];
      #pragma unroll
      for (int r = 0; r < 4; r++){
        int nl = w * 16 + quad * 4 + r;
        float v = acc[m][t][r] + bv;
        if (m) v = gelu_fast(v);
        tile[nl * WS + t * 16 + l16] = f2bf(v);
      }
    }
    __syncthreads();
    unsigned short* dst = m ? hbuf : sbuf;
    #pragma unroll
    for (int i = 0; i < 4; i++){
      int c = tid + 256 * i;
      int nl = c >> 4, j = c & 15;
      int node = nbb + nl;
      if (node < N){
        bf16x8 t8 = *(const bf16x8*)(tile + nl * WS + j * 8);
        *(bf16x8*)(dst + (size_t)node * D + j * 8) = t8;
        if (m){
          float f[8];
          #pragma unroll
          for (int q = 0; q < 8; q++) f[q] = bf2f((unsigned short)t8[q]);
          *(uint2*)(hb8 + (size_t)node * 128 + j * 8) = pack_fp8_8(f);
        }
      }
    }
    __syncthreads();
  }
}

// ---- edge-push SAGE layer: one block per 64-node bucket.
//      Phase 1: edge-parallel scatter of fp8 rows into f32 LDS accumulator
//      (ds_add_f32, uniform work, continuously pipelined loads).
//      Phase 2: build bf16 mean fragments from LDS -> dual-MFMA GEMM + LN
//      + epilogue (proven structure). ----
__global__ __launch_bounds__(256) void k_sage(
    const unsigned short* __restrict__ hin,
    const unsigned char* __restrict__ gin8,
    const unsigned* __restrict__ ebuf, const int* __restrict__ tot,
    const unsigned short* __restrict__ wp,
    const float* __restrict__ lb, const float* __restrict__ gamma,
    const float* __restrict__ beta,
    const unsigned short* __restrict__ sbuf,
    unsigned short* __restrict__ hout, unsigned char* __restrict__ hout8,
    float* __restrict__ fout, int N, int nbuck, int mode){
  __shared__ char smraw[39168];
  float* acc_s = (float*)smraw;                       // 64 x ALD f32 = 33792 B
  int* sdeg = (int*)(smraw + 33792);                  // 64 ints
  int* stot = (int*)(smraw + 34048);                  // 1024 ints
  int* red  = (int*)(smraw + 38144);                  // 256 ints
  unsigned short* stile = (unsigned short*)smraw;     // reuse (64 x WS bf16)
  float* ftile = (float*)smraw;                       // reuse (64 x FS f32)
  int tid = threadIdx.x;
  int b = blockIdx.x;
  // ---- bucket edge range: start = sum tot[0..b) ----
  for (int j = tid; j < nbuck; j += 256) stot[j] = tot[j];
  __syncthreads();
  int part = 0;
  for (int j = tid; j < b; j += 256) part += stot[j];
  red[tid] = part;
  __syncthreads();
  for (int ofs = 128; ofs > 0; ofs >>= 1){
    if (tid < ofs) red[tid] += red[tid + ofs];
    __syncthreads();
  }
  int estart = red[0];
  int eend = estart + stot[b];
  // ---- zero accumulator + degree ----
  float4* az = (float4*)acc_s;
  for (int i = tid; i < 64 * ALD / 4; i += 256) az[i] = (float4){0.f, 0.f, 0.f, 0.f};
  if (tid < 64) sdeg[tid] = 0;
  __syncthreads();
  // ---- phase 1: edge-parallel scatter (8 lanes per edge) ----
  {
    int g = tid >> 3, l8 = tid & 7;                   // 32 edge-groups
    const unsigned char* hp8 = gin8 + (size_t)l8 * 16;
    for (int e = estart + g; e < eend; e += 32){
      unsigned u = ebuf[e];
      int src = (int)(u & 0xFFFFu);
      int slot = (int)(u >> 16);
      uint4 v = *(const uint4*)(hp8 + (size_t)src * 128);
      if (l8 == 0) atomicAdd(&sdeg[slot], 1);
      f32x2 p0 = __builtin_amdgcn_cvt_pk_f32_fp8((int)v.x, false);
      f32x2 p1 = __builtin_amdgcn_cvt_pk_f32_fp8((int)v.x, true);
      f32x2 p2 = __builtin_amdgcn_cvt_pk_f32_fp8((int)v.y, false);
      f32x2 p3 = __builtin_amdgcn_cvt_pk_f32_fp8((int)v.y, true);
      f32x2 p4 = __builtin_amdgcn_cvt_pk_f32_fp8((int)v.z, false);
      f32x2 p5 = __builtin_amdgcn_cvt_pk_f32_fp8((int)v.z, true);
      f32x2 p6 = __builtin_amdgcn_cvt_pk_f32_fp8((int)v.w, false);
      f32x2 p7 = __builtin_amdgcn_cvt_pk_f32_fp8((int)v.w, true);
      float* ap = acc_s + (size_t)slot * ALD + l8 * 16;
      atomicAdd(ap + 0,  p0.x); atomicAdd(ap + 1,  p0.y);
      atomicAdd(ap + 2,  p1.x); atomicAdd(ap + 3,  p1.y);
      atomicAdd(ap + 4,  p2.x); atomicAdd(ap + 5,  p2.y);
      atomicAdd(ap + 6,  p3.x); atomicAdd(ap + 7,  p3.y);
      atomicAdd(ap + 8,  p4.x); atomicAdd(ap + 9,  p4.y);
      atomicAdd(ap + 10, p5.x); atomicAdd(ap + 11, p5.y);
      atomicAdd(ap + 12, p6.x); atomicAdd(ap + 13, p6.y);
      atomicAdd(ap + 14, p7.x); atomicAdd(ap + 15, p7.y);
    }
  }
  __syncthreads();
  // ---- phase 2: mean fragments -> GEMM + LN + epilogue ----
  int w = tid >> 6, lane = tid & 63, quad = lane >> 4, l16 = lane & 15;
  int nbb = b * 64;
  int mrow = w * 16 + l16;
  float inv = 1.f / (float)max(sdeg[mrow], 1);
  int arow = min(nbb + mrow, N - 1);
  bf16x8 am[4], ah[4];
  #pragma unroll
  for (int kk = 0; kk < 4; kk++){
    const float* ap = acc_s + (size_t)mrow * ALD + kk * 32 + quad * 8;
    float4 fa = *(const float4*)ap;
    float4 fb = *(const float4*)(ap + 4);
    bf16x8 a;
    a[0] = (short)f2bf(fa.x * inv); a[1] = (short)f2bf(fa.y * inv);
    a[2] = (short)f2bf(fa.z * inv); a[3] = (short)f2bf(fa.w * inv);
    a[4] = (short)f2bf(fb.x * inv); a[5] = (short)f2bf(fb.y * inv);
    a[6] = (short)f2bf(fb.z * inv); a[7] = (short)f2bf(fb.w * inv);
    am[kk] = a;
    ah[kk] = *(const bf16x8*)(hin + (size_t)arow * D + kk * 32 + quad * 8);
  }
  __syncthreads();   // acc/sdeg dead; LDS reusable for staging
  f32x4 acc[8];
  #pragma unroll
  for (int t = 0; t < 8; t++) acc[t] = (f32x4){0.f, 0.f, 0.f, 0.f};
  #pragma unroll
  for (int kk = 0; kk < 4; kk++){
    #pragma unroll
    for (int t = 0; t < 8; t++){
      size_t fo = (((size_t)(kk * 8 + t) * 2) * 64 + lane) * 8;
      bf16x8 bl = *(const bf16x8*)(wp + fo);
      bf16x8 br = *(const bf16x8*)(wp + fo + 512);
      acc[t] = __builtin_amdgcn_mfma_f32_16x16x32_bf16(am[kk], bl, acc[t], 0, 0, 0);
      acc[t] = __builtin_amdgcn_mfma_f32_16x16x32_bf16(ah[kk], br, acc[t], 0, 0, 0);
    }
  }
  float lbv[8], gv[8], bv[8];
  #pragma unroll
  for (int t = 0; t < 8; t++){
    lbv[t] = lb[t * 16 + l16];
    gv[t] = gamma[t * 16 + l16];
    bv[t] = beta[t * 16 + l16];
  }
  float mu[4], rs[4];
  #pragma unroll
  for (int r = 0; r < 4; r++){
    float s = 0.f, qq = 0.f;
    #pragma unroll
    for (int t = 0; t < 8; t++){
      float v = acc[t][r] + lbv[t];
      acc[t][r] = v;
      s += v; qq += v * v;
    }
    s += __shfl_xor(s, 1); qq += __shfl_xor(qq, 1);
    s += __shfl_xor(s, 2); qq += __shfl_xor(qq, 2);
    s += __shfl_xor(s, 4); qq += __shfl_xor(qq, 4);
    s += __shfl_xor(s, 8); qq += __shfl_xor(qq, 8);
    float m_ = s * (1.f / 128.f);
    mu[r] = m_;
    rs[r] = rsqrtf(qq * (1.f / 128.f) - m_ * m_ + 1e-5f);
  }
  if (mode == 0){
    #pragma unroll
    for (int t = 0; t < 8; t++)
      #pragma unroll
      for (int r = 0; r < 4; r++){
        int nl = w * 16 + quad * 4 + r;
        float v = (acc[t][r] - mu[r]) * rs[r] * gv[t] + bv[t];
        stile[nl * WS + t * 16 + l16] = f2bf(gelu_fast(v));
      }
    __syncthreads();
    #pragma unroll
    for (int i = 0; i < 4; i++){
      int c = tid + 256 * i;
      int nl = c >> 4, j = c & 15;
      int node = nbb + nl;
      if (node < N){
        bf16x8 t8 = *(const bf16x8*)(stile + nl * WS + j * 8);
        *(bf16x8*)(hout + (size_t)node * D + j * 8) = t8;
        float f[8];
        #pragma unroll
        for (int q = 0; q < 8; q++) f[q] = bf2f((unsigned short)t8[q]);
        *(uint2*)(hout8 + (size_t)node * 128 + j * 8) = pack_fp8_8(f);
      }
    }
  } else {
    #pragma unroll
    for (int i = 0; i < 4; i++){
      int c = tid + 256 * i;
      int nl = c >> 4, j = c & 15;
      int node = nbb + nl;
      bf16x8 v = (bf16x8){0,0,0,0,0,0,0,0};
      if (node < N) v = *(const bf16x8*)(sbuf + (size_t)node * D + j * 8);
      *(bf16x8*)(stile + nl * WS + j * 8) = v;
    }
    __syncthreads();
    float sc[8][4];
    #pragma unroll
    for (int t = 0; t < 8; t++)
      #pragma unroll
      for (int r = 0; r < 4; r++){
        int nl = w * 16 + quad * 4 + r;
        sc[t][r] = bf2f(stile[nl * WS + t * 16 + l16]);
      }
    __syncthreads();
    #pragma unroll
    for (int t = 0; t < 8; t++)
      #pragma unroll
      for (int r = 0; r < 4; r++){
        int nl = w * 16 + quad * 4 + r;
        float v = (acc[t][r] - mu[r]) * rs[r] * gv[t] + bv[t];
        ftile[nl * FS + t * 16 + l16] = gelu_fast(v + sc[t][r]);
      }
    __syncthreads();
    #pragma unroll
    for (int i = 0; i < 8; i++){
      int c = tid + 256 * i;
      int nl = c >> 5, j = c & 31;
      int node = nbb + nl;
      if (node < N)
        *(float4*)(fout + (size_t)node * D + j * 4) = *(const float4*)(ftile + nl * FS + j * 4);
    }
  }
}

extern "C" void kernel_launch(void* const* d_in, const int* in_sizes, int n_in,
                              void* d_out, int out_size, void* d_ws, size_t ws_size,
                              hipStream_t stream){
  const float* x     = (const float*)d_in[0];
  const int*   edges = (const int*)d_in[1];
  const float* dp_w  = (const float*)d_in[2];
  const float* dp_b  = (const float*)d_in[3];
  const float* sc_w  = (const float*)d_in[4];
  const float* sc_b  = (const float*)d_in[5];
  const float* g1_lw = (const float*)d_in[6];
  const float* g1_lb = (const float*)d_in[7];
  const float* g1_rw = (const float*)d_in[8];
  const float* n1_g  = (const float*)d_in[9];
  const float* n1_b  = (const float*)d_in[10];
  const float* g2_lw = (const float*)d_in[11];
  const float* g2_lb = (const float*)d_in[12];
  const float* g2_rw = (const float*)d_in[13];
  const float* n2_g  = (const float*)d_in[14];
  const float* n2_b  = (const float*)d_in[15];

  const int N = in_sizes[0] / D;
  const int E = in_sizes[1] / 2;
  const int* esrc = edges;
  const int* edst = edges + E;
  const int nbuck = (N + 63) >> 6;         // 64-node buckets
  const int epb = (E + PB - 1) / PB;

  char* base = (char*)d_ws;
  size_t cur = 0;
  auto carve = [&](size_t b) -> char* {
    char* p = base + cur;
    cur = (cur + b + 255) & ~(size_t)255;
    return p;
  };
  unsigned* ebuf  = (unsigned*)carve((size_t)E * 4);
  int* cnt        = (int*)carve((size_t)PB * nbuck * 4);
  int* offs_rel   = (int*)carve((size_t)PB * nbuck * 4);
  int* tot        = (int*)carve((size_t)nbuck * 4);
  unsigned short* wb    = (unsigned short*)carve((size_t)3 * 32768 * 2);
  unsigned short* hbuf  = (unsigned short*)carve((size_t)N * D * 2);
  unsigned short* h1buf = (unsigned short*)carve((size_t)N * D * 2);
  unsigned short* sbuf  = (unsigned short*)carve((size_t)N * D * 2);
  unsigned char*  hbuf8  = (unsigned char*)carve((size_t)N * 128);
  unsigned char*  h1buf8 = (unsigned char*)carve((size_t)N * 128);

  unsigned short* wp0 = wb;
  unsigned short* wp1 = wb + 32768;
  unsigned short* wp2 = wb + 2 * 32768;

  float* out = (float*)d_out;

  const int nin = (N + 63) / 64;

  k_prepcnt<<<48 + PB, 256, 0, stream>>>(sc_w, dp_w, g1_lw, g1_rw, g2_lw, g2_rw,
                                         wb, edst, cnt, E, nbuck, epb);
  k_scanA<<<nbuck, 128, 0, stream>>>(cnt, offs_rel, tot, nbuck);
  k_pscatgemm<<<PB + nin, 256, 0, stream>>>(esrc, edst, offs_rel, tot, ebuf,
                                            x, wp0, sc_b, dp_b, sbuf, hbuf, hbuf8,
                                            N, E, nbuck, epb);
  k_sage<<<nbuck, 256, 0, stream>>>(hbuf, hbuf8, ebuf, tot, wp1, g1_lb, n1_g, n1_b,
                                    nullptr, h1buf, h1buf8, nullptr, N, nbuck, 0);
  k_sage<<<nbuck, 256, 0, stream>>>(h1buf, h1buf8, ebuf, tot, wp2, g2_lb, n2_g, n2_b,
                                    sbuf, nullptr, nullptr, out, N, nbuck, 1);
}

// Round 9
// 227.147 us; speedup vs baseline: 5.4156x; 5.4156x over previous
//
#include <hip/hip_runtime.h>
#include <hip/hip_bf16.h>
#include <math.h>

#define D 128
#define WS 136            // LDS row stride in shorts
#define FS 132            // LDS row stride in floats
#define PB 128            // partition blocks

typedef __attribute__((ext_vector_type(8))) short bf16x8;
typedef __attribute__((ext_vector_type(4))) float f32x4;
typedef __attribute__((ext_vector_type(2))) float f32x2;

__device__ __forceinline__ unsigned short f2bf(float f){
  return (unsigned short)((__float_as_uint(f) + 0x8000u) >> 16);
}
__device__ __forceinline__ float bf2f(unsigned short h){
  return __uint_as_float(((unsigned)h) << 16);
}
__device__ __forceinline__ float bf2f_lo(unsigned v){
  return __uint_as_float(v << 16);
}
__device__ __forceinline__ float bf2f_hi(unsigned v){
  return __uint_as_float(v & 0xFFFF0000u);
}
__device__ __forceinline__ float gelu_fast(float v){
  float u = v * v;
  float arg = v * (1.5957691216f + 0.0713548163f * u);
  arg = fminf(arg, 60.0f);
  float e = __expf(arg);
  return v * e * __builtin_amdgcn_rcpf(e + 1.0f);
}
// pack 8 f32 -> 8 fp8 e4m3 (OCP on gfx950), RNE in HW
__device__ __forceinline__ uint2 pack_fp8_8(const float* f){
  int a = __builtin_amdgcn_cvt_pk_fp8_f32(f[0], f[1], 0, false);
  a = __builtin_amdgcn_cvt_pk_fp8_f32(f[2], f[3], a, true);
  int b = __builtin_amdgcn_cvt_pk_fp8_f32(f[4], f[5], 0, false);
  b = __builtin_amdgcn_cvt_pk_fp8_f32(f[6], f[7], b, true);
  return make_uint2((unsigned)a, (unsigned)b);
}

// ---- fused: weight convert (blocks 0..47) + bucket count (blocks 48..48+PB) ----
__global__ __launch_bounds__(256) void k_prepcnt(const float* s0, const float* s1,
    const float* s2, const float* s3, const float* s4, const float* s5,
    unsigned short* dst, const int* __restrict__ edst, int* __restrict__ cnt,
    int E, int nbuck, int epb){
  __shared__ int hist[512];
  if (blockIdx.x < 48){
    int gt = blockIdx.x * 256 + threadIdx.x;
    int m = gt >> 11;
    int r = gt & 2047;
    int f = r >> 6, lane = r & 63;
    int t = f & 7, kk = f >> 3;
    int row = t * 16 + (lane & 15);
    int col = kk * 32 + (lane >> 4) * 8;
    const float* src;
    if (m == 0) src = s0; else if (m == 1) src = s1; else if (m == 2) src = s2;
    else if (m == 3) src = s3; else if (m == 4) src = s4; else src = s5;
    src += row * 128 + col;
    float4 a = *(const float4*)src;
    float4 bb = *(const float4*)(src + 4);
    bf16x8 o;
    o[0] = (short)f2bf(a.x);  o[1] = (short)f2bf(a.y);
    o[2] = (short)f2bf(a.z);  o[3] = (short)f2bf(a.w);
    o[4] = (short)f2bf(bb.x); o[5] = (short)f2bf(bb.y);
    o[6] = (short)f2bf(bb.z); o[7] = (short)f2bf(bb.w);
    int pair = m >> 1, half = m & 1;
    *(bf16x8*)(dst + (size_t)pair * 32768 + (((size_t)f * 2 + half) * 64 + lane) * 8) = o;
    return;
  }
  int blk = blockIdx.x - 48;
  for (int b = threadIdx.x; b < nbuck; b += 256) hist[b] = 0;
  __syncthreads();
  int start = blk * epb;
  int end = min(E, start + epb);
  for (int e = start + threadIdx.x; e < end; e += 256)
    atomicAdd(&hist[edst[e] >> 7], 1);
  __syncthreads();
  for (int b = threadIdx.x; b < nbuck; b += 256) cnt[blk * nbuck + b] = hist[b];
}

// ---- per-bucket parallel scan over the PB partitions ----
__global__ __launch_bounds__(128) void k_scanA(const int* __restrict__ cnt,
    int* __restrict__ offs_rel, int* __restrict__ tot, int nbuck){
  __shared__ int sm[128];
  int b = blockIdx.x, t = threadIdx.x;
  int v = cnt[t * nbuck + b];
  sm[t] = v; __syncthreads();
  for (int ofs = 1; ofs < 128; ofs <<= 1){
    int u = (t >= ofs) ? sm[t - ofs] : 0;
    __syncthreads();
    sm[t] += u;
    __syncthreads();
  }
  offs_rel[t * nbuck + b] = sm[t] - v;
  if (t == 127) tot[b] = sm[127];
}

// ---- bucket scatter (LDS-only atomics); bucket bases computed in-block ----
__global__ __launch_bounds__(256) void k_pscatter(const int* __restrict__ esrc,
    const int* __restrict__ edst, const int* __restrict__ offs_rel,
    const int* __restrict__ tot, unsigned* __restrict__ ebuf,
    int E, int nbuck, int epb){
  __shared__ int stot[512];
  __shared__ int loff[512];
  for (int b = threadIdx.x; b < nbuck; b += 256) stot[b] = tot[b];
  __syncthreads();
  for (int b = threadIdx.x; b < nbuck; b += 256){
    int s = 0;
    for (int j = 0; j < b; j++) s += stot[j];
    loff[b] = s + offs_rel[blockIdx.x * nbuck + b];
  }
  __syncthreads();
  int start = blockIdx.x * epb;
  int end = min(E, start + epb);
  for (int e = start + threadIdx.x; e < end; e += 256){
    int s = esrc[e], d = edst[e];
    int b = d >> 7;
    int pos = atomicAdd(&loff[b], 1);
    ebuf[pos] = (unsigned)s | ((unsigned)(d & 127) << 16);
  }
}

// ---- fused: per-bucket counting sort -> csr/off (blocks < nbuck)
//      + input layer GEMM (blocks >= nbuck) ----
__global__ __launch_bounds__(256) void k_csrin(
    const unsigned* __restrict__ ebuf, const int* __restrict__ tot,
    int* __restrict__ off, int* __restrict__ csr,
    const float* __restrict__ x, const unsigned short* __restrict__ wp,
    const float* __restrict__ scb, const float* __restrict__ dpb,
    unsigned short* __restrict__ sbuf, unsigned short* __restrict__ hbuf,
    unsigned char* __restrict__ hb8,
    int N, int E, int nbuck){
  __shared__ int cnt[128], pref[128], curs[128];
  __shared__ int stot[512], red[256];
  __shared__ unsigned short tile[64 * WS];
  int tid = threadIdx.x;
  if ((int)blockIdx.x < nbuck){
    int b = blockIdx.x;
    for (int j = tid; j < nbuck; j += 256) stot[j] = tot[j];
    __syncthreads();
    int part = 0;
    for (int j = tid; j < b; j += 256) part += stot[j];
    red[tid] = part;
    __syncthreads();
    for (int ofs = 128; ofs > 0; ofs >>= 1){
      if (tid < ofs) red[tid] += red[tid + ofs];
      __syncthreads();
    }
    int start = red[0];
    int end = start + stot[b];
    if (tid < 128) cnt[tid] = 0;
    __syncthreads();
    for (int e = start + tid; e < end; e += 256)
      atomicAdd(&cnt[ebuf[e] >> 16], 1);
    __syncthreads();
    if (tid < 128) pref[tid] = cnt[tid];
    __syncthreads();
    for (int ofs = 1; ofs < 128; ofs <<= 1){
      int v = 0;
      if (tid < 128 && tid >= ofs) v = pref[tid - ofs];
      __syncthreads();
      if (tid < 128) pref[tid] += v;
      __syncthreads();
    }
    if (tid < 128){
      int ex = pref[tid] - cnt[tid];
      curs[tid] = ex;
      int node = b * 128 + tid;
      if (node < N) off[node] = start + ex;
    }
    if (b == 0 && tid == 0) off[N] = E;
    __syncthreads();
    for (int e = start + tid; e < end; e += 256){
      unsigned u = ebuf[e];
      int d = u >> 16;
      int p = atomicAdd(&curs[d], 1);
      csr[start + p] = (int)(u & 0xFFFFu);
    }
    return;
  }
  // ---- input GEMM part ----
  int bx = blockIdx.x - nbuck;
  int w = tid >> 6, lane = tid & 63, quad = lane >> 4, l16 = lane & 15;
  int nbb = bx * 64;
  int nb = nbb + w * 16;
  int arow = min(nb + l16, N - 1);
  f32x4 acc[2][8];
  #pragma unroll
  for (int m = 0; m < 2; m++)
    #pragma unroll
    for (int t = 0; t < 8; t++) acc[m][t] = (f32x4){0.f, 0.f, 0.f, 0.f};
  #pragma unroll
  for (int kk = 0; kk < 4; kk++){
    const float* xp = x + (size_t)arow * D + kk * 32 + quad * 8;
    float4 xa = *(const float4*)xp;
    float4 xb = *(const float4*)(xp + 4);
    bf16x8 a;
    a[0] = (short)f2bf(xa.x); a[1] = (short)f2bf(xa.y);
    a[2] = (short)f2bf(xa.z); a[3] = (short)f2bf(xa.w);
    a[4] = (short)f2bf(xb.x); a[5] = (short)f2bf(xb.y);
    a[6] = (short)f2bf(xb.z); a[7] = (short)f2bf(xb.w);
    #pragma unroll
    for (int t = 0; t < 8; t++){
      size_t fo = (((size_t)(kk * 8 + t) * 2) * 64 + lane) * 8;
      bf16x8 b0 = *(const bf16x8*)(wp + fo);
      bf16x8 b1 = *(const bf16x8*)(wp + fo + 512);
      acc[0][t] = __builtin_amdgcn_mfma_f32_16x16x32_bf16(a, b0, acc[0][t], 0, 0, 0);
      acc[1][t] = __builtin_amdgcn_mfma_f32_16x16x32_bf16(a, b1, acc[1][t], 0, 0, 0);
    }
  }
  #pragma unroll
  for (int m = 0; m < 2; m++){
    const float* bias = m ? dpb : scb;
    #pragma unroll
    for (int t = 0; t < 8; t++){
      float bv = bias[t * 16 + l16];
      #pragma unroll
      for (int r = 0; r < 4; r++){
        int nl = w * 16 + quad * 4 + r;
        float v = acc[m][t][r] + bv;
        if (m) v = gelu_fast(v);
        tile[nl * WS + t * 16 + l16] = f2bf(v);
      }
    }
    __syncthreads();
    unsigned short* dst = m ? hbuf : sbuf;
    #pragma unroll
    for (int i = 0; i < 4; i++){
      int c = tid + 256 * i;
      int nl = c >> 4, j = c & 15;
      int node = nbb + nl;
      if (node < N){
        bf16x8 t8 = *(const bf16x8*)(tile + nl * WS + j * 8);
        *(bf16x8*)(dst + (size_t)node * D + j * 8) = t8;
        if (m){
          float f[8];
          #pragma unroll
          for (int q = 0; q < 8; q++) f[q] = bf2f((unsigned short)t8[q]);
          *(uint2*)(hb8 + (size_t)node * 128 + j * 8) = pack_fp8_8(f);
        }
      }
    }
    __syncthreads();
  }
}

// ---- fused SAGE layer: phase1 gather from FP8 side-copy (8-lane groups,
//      128B rows: half the bytes/lines/addresses of bf16) -> LDS bf16 means;
//      phase2 dual-MFMA GEMM + LN + epilogue (root path stays bf16) ----
__global__ __launch_bounds__(256) void k_layer(
    const unsigned short* __restrict__ hin,
    const unsigned char* __restrict__ gin8,
    const int* __restrict__ off, const int* __restrict__ csr,
    const unsigned short* __restrict__ wp,
    const float* __restrict__ lb, const float* __restrict__ gamma,
    const float* __restrict__ beta,
    const unsigned short* __restrict__ sbuf,
    unsigned short* __restrict__ hout, unsigned char* __restrict__ hout8,
    float* __restrict__ fout, int N, int mode){
  extern __shared__ char smraw[];
  unsigned short* mtile = (unsigned short*)smraw;   // 64 x WS bf16 means
  unsigned short* stile = (unsigned short*)smraw;   // reused post-barrier
  float* ftile = (float*)smraw;                     // reused post-barrier (mode1)
  int tid = threadIdx.x;
  int nbb = blockIdx.x * 64;
  // ---- phase 1: gather (one node per 8-lane group, 2 passes, fp8 rows) ----
  {
    int g = tid >> 3, l8 = tid & 7;                 // 32 groups x 8 lanes
    const unsigned char* hp8 = gin8 + (size_t)l8 * 16;
    #pragma unroll
    for (int pass = 0; pass < 2; pass++){
      int nl = pass * 32 + g;
      int nodec = min(nbb + nl, N - 1);
      int s0 = off[nodec], s1 = off[nodec + 1];
      float acc[16];
      #pragma unroll
      for (int c = 0; c < 16; c++) acc[c] = 0.f;
      if (s1 > s0){
        int nn[8];
        #pragma unroll
        for (int i = 0; i < 8; i++) nn[i] = csr[min(s0 + i, s1 - 1)];
        for (int e = s0; e < s1; e += 8){
          uint4 v[8];
          #pragma unroll
          for (int i = 0; i < 8; i++)
            v[i] = *(const uint4*)(hp8 + (size_t)nn[i] * 128);
          #pragma unroll
          for (int i = 0; i < 8; i++) nn[i] = csr[min(e + 8 + i, s1 - 1)];
          #pragma unroll
          for (int i = 0; i < 8; i++){
            float m = (e + i < s1) ? 1.f : 0.f;
            f32x2 p0 = __builtin_amdgcn_cvt_pk_f32_fp8((int)v[i].x, false);
            f32x2 p1 = __builtin_amdgcn_cvt_pk_f32_fp8((int)v[i].x, true);
            f32x2 p2 = __builtin_amdgcn_cvt_pk_f32_fp8((int)v[i].y, false);
            f32x2 p3 = __builtin_amdgcn_cvt_pk_f32_fp8((int)v[i].y, true);
            f32x2 p4 = __builtin_amdgcn_cvt_pk_f32_fp8((int)v[i].z, false);
            f32x2 p5 = __builtin_amdgcn_cvt_pk_f32_fp8((int)v[i].z, true);
            f32x2 p6 = __builtin_amdgcn_cvt_pk_f32_fp8((int)v[i].w, false);
            f32x2 p7 = __builtin_amdgcn_cvt_pk_f32_fp8((int)v[i].w, true);
            acc[0]  = fmaf(m, p0.x, acc[0]);  acc[1]  = fmaf(m, p0.y, acc[1]);
            acc[2]  = fmaf(m, p1.x, acc[2]);  acc[3]  = fmaf(m, p1.y, acc[3]);
            acc[4]  = fmaf(m, p2.x, acc[4]);  acc[5]  = fmaf(m, p2.y, acc[5]);
            acc[6]  = fmaf(m, p3.x, acc[6]);  acc[7]  = fmaf(m, p3.y, acc[7]);
            acc[8]  = fmaf(m, p4.x, acc[8]);  acc[9]  = fmaf(m, p4.y, acc[9]);
            acc[10] = fmaf(m, p5.x, acc[10]); acc[11] = fmaf(m, p5.y, acc[11]);
            acc[12] = fmaf(m, p6.x, acc[12]); acc[13] = fmaf(m, p6.y, acc[13]);
            acc[14] = fmaf(m, p7.x, acc[14]); acc[15] = fmaf(m, p7.y, acc[15]);
          }
        }
      }
      float inv = 1.f / (float)max(s1 - s0, 1);
      bf16x8 o0, o1;
      #pragma unroll
      for (int c = 0; c < 8; c++){
        o0[c] = (short)f2bf(acc[c] * inv);
        o1[c] = (short)f2bf(acc[8 + c] * inv);
      }
      *(bf16x8*)(mtile + nl * WS + l8 * 16) = o0;
      *(bf16x8*)(mtile + nl * WS + l8 * 16 + 8) = o1;
    }
  }
  __syncthreads();
  // ---- phase 2: GEMM + LN + epilogue ----
  int w = tid >> 6, lane = tid & 63, quad = lane >> 4, l16 = lane & 15;
  int nb = nbb + w * 16;
  int arow = min(nb + l16, N - 1);
  int mrow = w * 16 + l16;
  bf16x8 am[4], ah[4];
  #pragma unroll
  for (int kk = 0; kk < 4; kk++){
    am[kk] = *(const bf16x8*)(mtile + mrow * WS + kk * 32 + quad * 8);
    ah[kk] = *(const bf16x8*)(hin + (size_t)arow * D + kk * 32 + quad * 8);
  }
  f32x4 acc[8];
  #pragma unroll
  for (int t = 0; t < 8; t++) acc[t] = (f32x4){0.f, 0.f, 0.f, 0.f};
  #pragma unroll
  for (int kk = 0; kk < 4; kk++){
    #pragma unroll
    for (int t = 0; t < 8; t++){
      size_t fo = (((size_t)(kk * 8 + t) * 2) * 64 + lane) * 8;
      bf16x8 bl = *(const bf16x8*)(wp + fo);
      bf16x8 br = *(const bf16x8*)(wp + fo + 512);
      acc[t] = __builtin_amdgcn_mfma_f32_16x16x32_bf16(am[kk], bl, acc[t], 0, 0, 0);
      acc[t] = __builtin_amdgcn_mfma_f32_16x16x32_bf16(ah[kk], br, acc[t], 0, 0, 0);
    }
  }
  float lbv[8], gv[8], bv[8];
  #pragma unroll
  for (int t = 0; t < 8; t++){
    lbv[t] = lb[t * 16 + l16];
    gv[t] = gamma[t * 16 + l16];
    bv[t] = beta[t * 16 + l16];
  }
  float mu[4], rs[4];
  #pragma unroll
  for (int r = 0; r < 4; r++){
    float s = 0.f, qq = 0.f;
    #pragma unroll
    for (int t = 0; t < 8; t++){
      float v = acc[t][r] + lbv[t];
      acc[t][r] = v;
      s += v; qq += v * v;
    }
    s += __shfl_xor(s, 1); qq += __shfl_xor(qq, 1);
    s += __shfl_xor(s, 2); qq += __shfl_xor(qq, 2);
    s += __shfl_xor(s, 4); qq += __shfl_xor(qq, 4);
    s += __shfl_xor(s, 8); qq += __shfl_xor(qq, 8);
    float m_ = s * (1.f / 128.f);
    mu[r] = m_;
    rs[r] = rsqrtf(qq * (1.f / 128.f) - m_ * m_ + 1e-5f);
  }
  __syncthreads();   // mean tile dead; LDS reusable for epilogue
  if (mode == 0){
    #pragma unroll
    for (int t = 0; t < 8; t++)
      #pragma unroll
      for (int r = 0; r < 4; r++){
        int nl = w * 16 + quad * 4 + r;
        float v = (acc[t][r] - mu[r]) * rs[r] * gv[t] + bv[t];
        stile[nl * WS + t * 16 + l16] = f2bf(gelu_fast(v));
      }
    __syncthreads();
    #pragma unroll
    for (int i = 0; i < 4; i++){
      int c = tid + 256 * i;
      int nl = c >> 4, j = c & 15;
      int node = nbb + nl;
      if (node < N){
        bf16x8 t8 = *(const bf16x8*)(stile + nl * WS + j * 8);
        *(bf16x8*)(hout + (size_t)node * D + j * 8) = t8;
        float f[8];
        #pragma unroll
        for (int q = 0; q < 8; q++) f[q] = bf2f((unsigned short)t8[q]);
        *(uint2*)(hout8 + (size_t)node * 128 + j * 8) = pack_fp8_8(f);
      }
    }
  } else {
    #pragma unroll
    for (int i = 0; i < 4; i++){
      int c = tid + 256 * i;
      int nl = c >> 4, j = c & 15;
      int node = nbb + nl;
      bf16x8 v = (bf16x8){0,0,0,0,0,0,0,0};
      if (node < N) v = *(const bf16x8*)(sbuf + (size_t)node * D + j * 8);
      *(bf16x8*)(stile + nl * WS + j * 8) = v;
    }
    __syncthreads();
    float sc[8][4];
    #pragma unroll
    for (int t = 0; t < 8; t++)
      #pragma unroll
      for (int r = 0; r < 4; r++){
        int nl = w * 16 + quad * 4 + r;
        sc[t][r] = bf2f(stile[nl * WS + t * 16 + l16]);
      }
    __syncthreads();
    #pragma unroll
    for (int t = 0; t < 8; t++)
      #pragma unroll
      for (int r = 0; r < 4; r++){
        int nl = w * 16 + quad * 4 + r;
        float v = (acc[t][r] - mu[r]) * rs[r] * gv[t] + bv[t];
        ftile[nl * FS + t * 16 + l16] = gelu_fast(v + sc[t][r]);
      }
    __syncthreads();
    #pragma unroll
    for (int i = 0; i < 8; i++){
      int c = tid + 256 * i;
      int nl = c >> 5, j = c & 31;
      int node = nbb + nl;
      if (node < N)
        *(float4*)(fout + (size_t)node * D + j * 4) = *(const float4*)(ftile + nl * FS + j * 4);
    }
  }
}

extern "C" void kernel_launch(void* const* d_in, const int* in_sizes, int n_in,
                              void* d_out, int out_size, void* d_ws, size_t ws_size,
                              hipStream_t stream){
  const float* x     = (const float*)d_in[0];
  const int*   edges = (const int*)d_in[1];
  const float* dp_w  = (const float*)d_in[2];
  const float* dp_b  = (const float*)d_in[3];
  const float* sc_w  = (const float*)d_in[4];
  const float* sc_b  = (const float*)d_in[5];
  const float* g1_lw = (const float*)d_in[6];
  const float* g1_lb = (const float*)d_in[7];
  const float* g1_rw = (const float*)d_in[8];
  const float* n1_g  = (const float*)d_in[9];
  const float* n1_b  = (const float*)d_in[10];
  const float* g2_lw = (const float*)d_in[11];
  const float* g2_lb = (const float*)d_in[12];
  const float* g2_rw = (const float*)d_in[13];
  const float* n2_g  = (const float*)d_in[14];
  const float* n2_b  = (const float*)d_in[15];

  const int N = in_sizes[0] / D;
  const int E = in_sizes[1] / 2;
  const int* esrc = edges;
  const int* edst = edges + E;
  const int nbuck = (N + 127) >> 7;
  const int epb = (E + PB - 1) / PB;

  char* base = (char*)d_ws;
  size_t cur = 0;
  auto carve = [&](size_t b) -> char* {
    char* p = base + cur;
    cur = (cur + b + 255) & ~(size_t)255;
    return p;
  };
  unsigned* ebuf  = (unsigned*)carve((size_t)E * 4);
  int* cnt        = (int*)carve((size_t)PB * nbuck * 4);
  int* offs_rel   = (int*)carve((size_t)PB * nbuck * 4);
  int* tot        = (int*)carve((size_t)nbuck * 4);
  int* off        = (int*)carve((size_t)(N + 1) * 4);
  int* csr        = (int*)carve((size_t)E * 4);
  unsigned short* wb    = (unsigned short*)carve((size_t)3 * 32768 * 2);
  unsigned short* hbuf  = (unsigned short*)carve((size_t)N * D * 2);
  unsigned short* h1buf = (unsigned short*)carve((size_t)N * D * 2);
  unsigned short* sbuf  = (unsigned short*)carve((size_t)N * D * 2);
  unsigned char*  hbuf8  = (unsigned char*)carve((size_t)N * 128);
  unsigned char*  h1buf8 = (unsigned char*)carve((size_t)N * 128);

  unsigned short* wp0 = wb;
  unsigned short* wp1 = wb + 32768;
  unsigned short* wp2 = wb + 2 * 32768;

  float* out = (float*)d_out;

  k_prepcnt<<<48 + PB, 256, 0, stream>>>(sc_w, dp_w, g1_lw, g1_rw, g2_lw, g2_rw,
                                         wb, edst, cnt, E, nbuck, epb);
  k_scanA<<<nbuck, 128, 0, stream>>>(cnt, offs_rel, tot, nbuck);
  k_pscatter<<<PB, 256, 0, stream>>>(esrc, edst, offs_rel, tot, ebuf, E, nbuck, epb);

  const int nin = (N + 63) / 64;
  k_csrin<<<nbuck + nin, 256, 0, stream>>>(ebuf, tot, off, csr,
                                           x, wp0, sc_b, dp_b, sbuf, hbuf, hbuf8,
                                           N, E, nbuck);

  k_layer<<<nin, 256, 17408, stream>>>(hbuf, hbuf8, off, csr, wp1, g1_lb, n1_g, n1_b,
                                       nullptr, h1buf, h1buf8, nullptr, N, 0);
  k_layer<<<nin, 256, 33792, stream>>>(h1buf, h1buf8, off, csr, wp2, g2_lb, n2_g, n2_b,
                                       sbuf, nullptr, nullptr, out, N, 1);
}

// Round 10
// 222.608 us; speedup vs baseline: 5.5260x; 1.0204x over previous
//
#include <hip/hip_runtime.h>
#include <hip/hip_bf16.h>
#include <math.h>

#define D 128
#define WS 136            // LDS row stride in shorts
#define FS 132            // LDS row stride in floats
#define PB 128            // partition blocks

typedef __attribute__((ext_vector_type(8))) short bf16x8;
typedef __attribute__((ext_vector_type(4))) float f32x4;
typedef __attribute__((ext_vector_type(2))) float f32x2;

__device__ __forceinline__ unsigned short f2bf(float f){
  return (unsigned short)((__float_as_uint(f) + 0x8000u) >> 16);
}
__device__ __forceinline__ float bf2f(unsigned short h){
  return __uint_as_float(((unsigned)h) << 16);
}
__device__ __forceinline__ float gelu_fast(float v){
  float u = v * v;
  float arg = v * (1.5957691216f + 0.0713548163f * u);
  arg = fminf(arg, 60.0f);
  float e = __expf(arg);
  return v * e * __builtin_amdgcn_rcpf(e + 1.0f);
}
// pack 8 f32 -> 8 fp8 e4m3 (OCP on gfx950), RNE in HW
__device__ __forceinline__ uint2 pack_fp8_8(const float* f){
  int a = __builtin_amdgcn_cvt_pk_fp8_f32(f[0], f[1], 0, false);
  a = __builtin_amdgcn_cvt_pk_fp8_f32(f[2], f[3], a, true);
  int b = __builtin_amdgcn_cvt_pk_fp8_f32(f[4], f[5], 0, false);
  b = __builtin_amdgcn_cvt_pk_fp8_f32(f[6], f[7], b, true);
  return make_uint2((unsigned)a, (unsigned)b);
}

// ---- fused: weight convert (blocks 0..47) + bucket count (blocks 48..48+PB) ----
__global__ __launch_bounds__(256) void k_prepcnt(const float* s0, const float* s1,
    const float* s2, const float* s3, const float* s4, const float* s5,
    unsigned short* dst, const int* __restrict__ edst, int* __restrict__ cnt,
    int E, int nbuck, int epb){
  __shared__ int hist[512];
  if (blockIdx.x < 48){
    int gt = blockIdx.x * 256 + threadIdx.x;
    int m = gt >> 11;
    int r = gt & 2047;
    int f = r >> 6, lane = r & 63;
    int t = f & 7, kk = f >> 3;
    int row = t * 16 + (lane & 15);
    int col = kk * 32 + (lane >> 4) * 8;
    const float* src;
    if (m == 0) src = s0; else if (m == 1) src = s1; else if (m == 2) src = s2;
    else if (m == 3) src = s3; else if (m == 4) src = s4; else src = s5;
    src += row * 128 + col;
    float4 a = *(const float4*)src;
    float4 bb = *(const float4*)(src + 4);
    bf16x8 o;
    o[0] = (short)f2bf(a.x);  o[1] = (short)f2bf(a.y);
    o[2] = (short)f2bf(a.z);  o[3] = (short)f2bf(a.w);
    o[4] = (short)f2bf(bb.x); o[5] = (short)f2bf(bb.y);
    o[6] = (short)f2bf(bb.z); o[7] = (short)f2bf(bb.w);
    int pair = m >> 1, half = m & 1;
    *(bf16x8*)(dst + (size_t)pair * 32768 + (((size_t)f * 2 + half) * 64 + lane) * 8) = o;
    return;
  }
  int blk = blockIdx.x - 48;
  for (int b = threadIdx.x; b < nbuck; b += 256) hist[b] = 0;
  __syncthreads();
  int start = blk * epb;
  int end = min(E, start + epb);
  for (int e = start + threadIdx.x; e < end; e += 256)
    atomicAdd(&hist[edst[e] >> 7], 1);
  __syncthreads();
  for (int b = threadIdx.x; b < nbuck; b += 256) cnt[blk * nbuck + b] = hist[b];
}

// ---- per-bucket parallel scan over the PB partitions ----
__global__ __launch_bounds__(128) void k_scanA(const int* __restrict__ cnt,
    int* __restrict__ offs_rel, int* __restrict__ tot, int nbuck){
  __shared__ int sm[128];
  int b = blockIdx.x, t = threadIdx.x;
  int v = cnt[t * nbuck + b];
  sm[t] = v; __syncthreads();
  for (int ofs = 1; ofs < 128; ofs <<= 1){
    int u = (t >= ofs) ? sm[t - ofs] : 0;
    __syncthreads();
    sm[t] += u;
    __syncthreads();
  }
  offs_rel[t * nbuck + b] = sm[t] - v;
  if (t == 127) tot[b] = sm[127];
}

// ---- bucket scatter (LDS-only atomics); bucket bases computed in-block ----
__global__ __launch_bounds__(256) void k_pscatter(const int* __restrict__ esrc,
    const int* __restrict__ edst, const int* __restrict__ offs_rel,
    const int* __restrict__ tot, unsigned* __restrict__ ebuf,
    int E, int nbuck, int epb){
  __shared__ int stot[512];
  __shared__ int loff[512];
  for (int b = threadIdx.x; b < nbuck; b += 256) stot[b] = tot[b];
  __syncthreads();
  for (int b = threadIdx.x; b < nbuck; b += 256){
    int s = 0;
    for (int j = 0; j < b; j++) s += stot[j];
    loff[b] = s + offs_rel[blockIdx.x * nbuck + b];
  }
  __syncthreads();
  int start = blockIdx.x * epb;
  int end = min(E, start + epb);
  for (int e = start + threadIdx.x; e < end; e += 256){
    int s = esrc[e], d = edst[e];
    int b = d >> 7;
    int pos = atomicAdd(&loff[b], 1);
    ebuf[pos] = (unsigned)s | ((unsigned)(d & 127) << 16);
  }
}

// ---- fused: per-bucket counting sort -> csr/off (blocks < nbuck)
//      + input layer GEMM (blocks >= nbuck) ----
__global__ __launch_bounds__(256) void k_csrin(
    const unsigned* __restrict__ ebuf, const int* __restrict__ tot,
    int* __restrict__ off, int* __restrict__ csr,
    const float* __restrict__ x, const unsigned short* __restrict__ wp,
    const float* __restrict__ scb, const float* __restrict__ dpb,
    unsigned short* __restrict__ sbuf, unsigned short* __restrict__ hbuf,
    unsigned char* __restrict__ hb8,
    int N, int E, int nbuck){
  __shared__ int cnt[128], pref[128], curs[128];
  __shared__ int stot[512], red[256];
  __shared__ unsigned short tile[64 * WS];
  int tid = threadIdx.x;
  if ((int)blockIdx.x < nbuck){
    int b = blockIdx.x;
    for (int j = tid; j < nbuck; j += 256) stot[j] = tot[j];
    __syncthreads();
    int part = 0;
    for (int j = tid; j < b; j += 256) part += stot[j];
    red[tid] = part;
    __syncthreads();
    for (int ofs = 128; ofs > 0; ofs >>= 1){
      if (tid < ofs) red[tid] += red[tid + ofs];
      __syncthreads();
    }
    int start = red[0];
    int end = start + stot[b];
    if (tid < 128) cnt[tid] = 0;
    __syncthreads();
    for (int e = start + tid; e < end; e += 256)
      atomicAdd(&cnt[ebuf[e] >> 16], 1);
    __syncthreads();
    if (tid < 128) pref[tid] = cnt[tid];
    __syncthreads();
    for (int ofs = 1; ofs < 128; ofs <<= 1){
      int v = 0;
      if (tid < 128 && tid >= ofs) v = pref[tid - ofs];
      __syncthreads();
      if (tid < 128) pref[tid] += v;
      __syncthreads();
    }
    if (tid < 128){
      int ex = pref[tid] - cnt[tid];
      curs[tid] = ex;
      int node = b * 128 + tid;
      if (node < N) off[node] = start + ex;
    }
    if (b == 0 && tid == 0) off[N] = E;
    __syncthreads();
    for (int e = start + tid; e < end; e += 256){
      unsigned u = ebuf[e];
      int d = u >> 16;
      int p = atomicAdd(&curs[d], 1);
      csr[start + p] = (int)(u & 0xFFFFu);
    }
    return;
  }
  // ---- input GEMM part ----
  int bx = blockIdx.x - nbuck;
  int w = tid >> 6, lane = tid & 63, quad = lane >> 4, l16 = lane & 15;
  int nbb = bx * 64;
  int nb = nbb + w * 16;
  int arow = min(nb + l16, N - 1);
  f32x4 acc[2][8];
  #pragma unroll
  for (int m = 0; m < 2; m++)
    #pragma unroll
    for (int t = 0; t < 8; t++) acc[m][t] = (f32x4){0.f, 0.f, 0.f, 0.f};
  #pragma unroll
  for (int kk = 0; kk < 4; kk++){
    const float* xp = x + (size_t)arow * D + kk * 32 + quad * 8;
    float4 xa = *(const float4*)xp;
    float4 xb = *(const float4*)(xp + 4);
    bf16x8 a;
    a[0] = (short)f2bf(xa.x); a[1] = (short)f2bf(xa.y);
    a[2] = (short)f2bf(xa.z); a[3] = (short)f2bf(xa.w);
    a[4] = (short)f2bf(xb.x); a[5] = (short)f2bf(xb.y);
    a[6] = (short)f2bf(xb.z); a[7] = (short)f2bf(xb.w);
    #pragma unroll
    for (int t = 0; t < 8; t++){
      size_t fo = (((size_t)(kk * 8 + t) * 2) * 64 + lane) * 8;
      bf16x8 b0 = *(const bf16x8*)(wp + fo);
      bf16x8 b1 = *(const bf16x8*)(wp + fo + 512);
      acc[0][t] = __builtin_amdgcn_mfma_f32_16x16x32_bf16(a, b0, acc[0][t], 0, 0, 0);
      acc[1][t] = __builtin_amdgcn_mfma_f32_16x16x32_bf16(a, b1, acc[1][t], 0, 0, 0);
    }
  }
  #pragma unroll
  for (int m = 0; m < 2; m++){
    const float* bias = m ? dpb : scb;
    #pragma unroll
    for (int t = 0; t < 8; t++){
      float bv = bias[t * 16 + l16];
      #pragma unroll
      for (int r = 0; r < 4; r++){
        int nl = w * 16 + quad * 4 + r;
        float v = acc[m][t][r] + bv;
        if (m) v = gelu_fast(v);
        tile[nl * WS + t * 16 + l16] = f2bf(v);
      }
    }
    __syncthreads();
    unsigned short* dst = m ? hbuf : sbuf;
    #pragma unroll
    for (int i = 0; i < 4; i++){
      int c = tid + 256 * i;
      int nl = c >> 4, j = c & 15;
      int node = nbb + nl;
      if (node < N){
        bf16x8 t8 = *(const bf16x8*)(tile + nl * WS + j * 8);
        *(bf16x8*)(dst + (size_t)node * D + j * 8) = t8;
        if (m){
          float f[8];
          #pragma unroll
          for (int q = 0; q < 8; q++) f[q] = bf2f((unsigned short)t8[q]);
          *(uint2*)(hb8 + (size_t)node * 128 + j * 8) = pack_fp8_8(f);
        }
      }
    }
    __syncthreads();
  }
}

// ---- fused SAGE layer: phase1 gather from FP8 side-copy in TWO half-dim
//      passes (64B rows -> 3.2MB working set per pass, fits per-XCD L2;
//      grid is phase-coherent since all blocks are co-resident);
//      phase2 dual-MFMA GEMM + LN + epilogue (root path stays bf16) ----
__global__ __launch_bounds__(256) void k_layer(
    const unsigned short* __restrict__ hin,
    const unsigned char* __restrict__ gin8,
    const int* __restrict__ off, const int* __restrict__ csr,
    const unsigned short* __restrict__ wp,
    const float* __restrict__ lb, const float* __restrict__ gamma,
    const float* __restrict__ beta,
    const unsigned short* __restrict__ sbuf,
    unsigned short* __restrict__ hout, unsigned char* __restrict__ hout8,
    float* __restrict__ fout, int N, int mode){
  extern __shared__ char smraw[];
  unsigned short* mtile = (unsigned short*)smraw;   // 64 x WS bf16 means
  unsigned short* stile = (unsigned short*)smraw;   // reused post-barrier
  float* ftile = (float*)smraw;                     // reused post-barrier (mode1)
  int tid = threadIdx.x;
  int nbb = blockIdx.x * 64;
  // ---- phase 1: gather (8-lane groups; 2 half-dim passes x 2 node passes;
  //      each lane loads 8B -> one 64B line per row-half) ----
  {
    int g = tid >> 3, l8 = tid & 7;                 // 32 groups x 8 lanes
    #pragma unroll
    for (int half = 0; half < 2; half++){
      const unsigned char* hp8 = gin8 + half * 64 + (size_t)l8 * 8;
      #pragma unroll
      for (int pass = 0; pass < 2; pass++){
        int nl = pass * 32 + g;
        int nodec = min(nbb + nl, N - 1);
        int s0 = off[nodec], s1 = off[nodec + 1];
        float acc[8];
        #pragma unroll
        for (int c = 0; c < 8; c++) acc[c] = 0.f;
        if (s1 > s0){
          int nn[8];
          #pragma unroll
          for (int i = 0; i < 8; i++) nn[i] = csr[min(s0 + i, s1 - 1)];
          for (int e = s0; e < s1; e += 8){
            uint2 v[8];
            #pragma unroll
            for (int i = 0; i < 8; i++)
              v[i] = *(const uint2*)(hp8 + (size_t)nn[i] * 128);
            #pragma unroll
            for (int i = 0; i < 8; i++) nn[i] = csr[min(e + 8 + i, s1 - 1)];
            #pragma unroll
            for (int i = 0; i < 8; i++){
              float m = (e + i < s1) ? 1.f : 0.f;
              f32x2 p0 = __builtin_amdgcn_cvt_pk_f32_fp8((int)v[i].x, false);
              f32x2 p1 = __builtin_amdgcn_cvt_pk_f32_fp8((int)v[i].x, true);
              f32x2 p2 = __builtin_amdgcn_cvt_pk_f32_fp8((int)v[i].y, false);
              f32x2 p3 = __builtin_amdgcn_cvt_pk_f32_fp8((int)v[i].y, true);
              acc[0] = fmaf(m, p0.x, acc[0]); acc[1] = fmaf(m, p0.y, acc[1]);
              acc[2] = fmaf(m, p1.x, acc[2]); acc[3] = fmaf(m, p1.y, acc[3]);
              acc[4] = fmaf(m, p2.x, acc[4]); acc[5] = fmaf(m, p2.y, acc[5]);
              acc[6] = fmaf(m, p3.x, acc[6]); acc[7] = fmaf(m, p3.y, acc[7]);
            }
          }
        }
        float inv = 1.f / (float)max(s1 - s0, 1);
        bf16x8 o;
        #pragma unroll
        for (int c = 0; c < 8; c++) o[c] = (short)f2bf(acc[c] * inv);
        *(bf16x8*)(mtile + nl * WS + half * 64 + l8 * 8) = o;
      }
    }
  }
  __syncthreads();
  // ---- phase 2: GEMM + LN + epilogue ----
  int w = tid >> 6, lane = tid & 63, quad = lane >> 4, l16 = lane & 15;
  int nb = nbb + w * 16;
  int arow = min(nb + l16, N - 1);
  int mrow = w * 16 + l16;
  bf16x8 am[4], ah[4];
  #pragma unroll
  for (int kk = 0; kk < 4; kk++){
    am[kk] = *(const bf16x8*)(mtile + mrow * WS + kk * 32 + quad * 8);
    ah[kk] = *(const bf16x8*)(hin + (size_t)arow * D + kk * 32 + quad * 8);
  }
  f32x4 acc[8];
  #pragma unroll
  for (int t = 0; t < 8; t++) acc[t] = (f32x4){0.f, 0.f, 0.f, 0.f};
  #pragma unroll
  for (int kk = 0; kk < 4; kk++){
    #pragma unroll
    for (int t = 0; t < 8; t++){
      size_t fo = (((size_t)(kk * 8 + t) * 2) * 64 + lane) * 8;
      bf16x8 bl = *(const bf16x8*)(wp + fo);
      bf16x8 br = *(const bf16x8*)(wp + fo + 512);
      acc[t] = __builtin_amdgcn_mfma_f32_16x16x32_bf16(am[kk], bl, acc[t], 0, 0, 0);
      acc[t] = __builtin_amdgcn_mfma_f32_16x16x32_bf16(ah[kk], br, acc[t], 0, 0, 0);
    }
  }
  float lbv[8], gv[8], bv[8];
  #pragma unroll
  for (int t = 0; t < 8; t++){
    lbv[t] = lb[t * 16 + l16];
    gv[t] = gamma[t * 16 + l16];
    bv[t] = beta[t * 16 + l16];
  }
  float mu[4], rs[4];
  #pragma unroll
  for (int r = 0; r < 4; r++){
    float s = 0.f, qq = 0.f;
    #pragma unroll
    for (int t = 0; t < 8; t++){
      float v = acc[t][r] + lbv[t];
      acc[t][r] = v;
      s += v; qq += v * v;
    }
    s += __shfl_xor(s, 1); qq += __shfl_xor(qq, 1);
    s += __shfl_xor(s, 2); qq += __shfl_xor(qq, 2);
    s += __shfl_xor(s, 4); qq += __shfl_xor(qq, 4);
    s += __shfl_xor(s, 8); qq += __shfl_xor(qq, 8);
    float m_ = s * (1.f / 128.f);
    mu[r] = m_;
    rs[r] = rsqrtf(qq * (1.f / 128.f) - m_ * m_ + 1e-5f);
  }
  __syncthreads();   // mean tile dead; LDS reusable for epilogue
  if (mode == 0){
    #pragma unroll
    for (int t = 0; t < 8; t++)
      #pragma unroll
      for (int r = 0; r < 4; r++){
        int nl = w * 16 + quad * 4 + r;
        float v = (acc[t][r] - mu[r]) * rs[r] * gv[t] + bv[t];
        stile[nl * WS + t * 16 + l16] = f2bf(gelu_fast(v));
      }
    __syncthreads();
    #pragma unroll
    for (int i = 0; i < 4; i++){
      int c = tid + 256 * i;
      int nl = c >> 4, j = c & 15;
      int node = nbb + nl;
      if (node < N){
        bf16x8 t8 = *(const bf16x8*)(stile + nl * WS + j * 8);
        *(bf16x8*)(hout + (size_t)node * D + j * 8) = t8;
        float f[8];
        #pragma unroll
        for (int q = 0; q < 8; q++) f[q] = bf2f((unsigned short)t8[q]);
        *(uint2*)(hout8 + (size_t)node * 128 + j * 8) = pack_fp8_8(f);
      }
    }
  } else {
    #pragma unroll
    for (int i = 0; i < 4; i++){
      int c = tid + 256 * i;
      int nl = c >> 4, j = c & 15;
      int node = nbb + nl;
      bf16x8 v = (bf16x8){0,0,0,0,0,0,0,0};
      if (node < N) v = *(const bf16x8*)(sbuf + (size_t)node * D + j * 8);
      *(bf16x8*)(stile + nl * WS + j * 8) = v;
    }
    __syncthreads();
    float sc[8][4];
    #pragma unroll
    for (int t = 0; t < 8; t++)
      #pragma unroll
      for (int r = 0; r < 4; r++){
        int nl = w * 16 + quad * 4 + r;
        sc[t][r] = bf2f(stile[nl * WS + t * 16 + l16]);
      }
    __syncthreads();
    #pragma unroll
    for (int t = 0; t < 8; t++)
      #pragma unroll
      for (int r = 0; r < 4; r++){
        int nl = w * 16 + quad * 4 + r;
        float v = (acc[t][r] - mu[r]) * rs[r] * gv[t] + bv[t];
        ftile[nl * FS + t * 16 + l16] = gelu_fast(v + sc[t][r]);
      }
    __syncthreads();
    #pragma unroll
    for (int i = 0; i < 8; i++){
      int c = tid + 256 * i;
      int nl = c >> 5, j = c & 31;
      int node = nbb + nl;
      if (node < N)
        *(float4*)(fout + (size_t)node * D + j * 4) = *(const float4*)(ftile + nl * FS + j * 4);
    }
  }
}

extern "C" void kernel_launch(void* const* d_in, const int* in_sizes, int n_in,
                              void* d_out, int out_size, void* d_ws, size_t ws_size,
                              hipStream_t stream){
  const float* x     = (const float*)d_in[0];
  const int*   edges = (const int*)d_in[1];
  const float* dp_w  = (const float*)d_in[2];
  const float* dp_b  = (const float*)d_in[3];
  const float* sc_w  = (const float*)d_in[4];
  const float* sc_b  = (const float*)d_in[5];
  const float* g1_lw = (const float*)d_in[6];
  const float* g1_lb = (const float*)d_in[7];
  const float* g1_rw = (const float*)d_in[8];
  const float* n1_g  = (const float*)d_in[9];
  const float* n1_b  = (const float*)d_in[10];
  const float* g2_lw = (const float*)d_in[11];
  const float* g2_lb = (const float*)d_in[12];
  const float* g2_rw = (const float*)d_in[13];
  const float* n2_g  = (const float*)d_in[14];
  const float* n2_b  = (const float*)d_in[15];

  const int N = in_sizes[0] / D;
  const int E = in_sizes[1] / 2;
  const int* esrc = edges;
  const int* edst = edges + E;
  const int nbuck = (N + 127) >> 7;
  const int epb = (E + PB - 1) / PB;

  char* base = (char*)d_ws;
  size_t cur = 0;
  auto carve = [&](size_t b) -> char* {
    char* p = base + cur;
    cur = (cur + b + 255) & ~(size_t)255;
    return p;
  };
  unsigned* ebuf  = (unsigned*)carve((size_t)E * 4);
  int* cnt        = (int*)carve((size_t)PB * nbuck * 4);
  int* offs_rel   = (int*)carve((size_t)PB * nbuck * 4);
  int* tot        = (int*)carve((size_t)nbuck * 4);
  int* off        = (int*)carve((size_t)(N + 1) * 4);
  int* csr        = (int*)carve((size_t)E * 4);
  unsigned short* wb    = (unsigned short*)carve((size_t)3 * 32768 * 2);
  unsigned short* hbuf  = (unsigned short*)carve((size_t)N * D * 2);
  unsigned short* h1buf = (unsigned short*)carve((size_t)N * D * 2);
  unsigned short* sbuf  = (unsigned short*)carve((size_t)N * D * 2);
  unsigned char*  hbuf8  = (unsigned char*)carve((size_t)N * 128);
  unsigned char*  h1buf8 = (unsigned char*)carve((size_t)N * 128);

  unsigned short* wp0 = wb;
  unsigned short* wp1 = wb + 32768;
  unsigned short* wp2 = wb + 2 * 32768;

  float* out = (float*)d_out;

  k_prepcnt<<<48 + PB, 256, 0, stream>>>(sc_w, dp_w, g1_lw, g1_rw, g2_lw, g2_rw,
                                         wb, edst, cnt, E, nbuck, epb);
  k_scanA<<<nbuck, 128, 0, stream>>>(cnt, offs_rel, tot, nbuck);
  k_pscatter<<<PB, 256, 0, stream>>>(esrc, edst, offs_rel, tot, ebuf, E, nbuck, epb);

  const int nin = (N + 63) / 64;
  k_csrin<<<nbuck + nin, 256, 0, stream>>>(ebuf, tot, off, csr,
                                           x, wp0, sc_b, dp_b, sbuf, hbuf, hbuf8,
                                           N, E, nbuck);

  k_layer<<<nin, 256, 17408, stream>>>(hbuf, hbuf8, off, csr, wp1, g1_lb, n1_g, n1_b,
                                       nullptr, h1buf, h1buf8, nullptr, N, 0);
  k_layer<<<nin, 256, 33792, stream>>>(h1buf, h1buf8, off, csr, wp2, g2_lb, n2_g, n2_b,
                                       sbuf, nullptr, nullptr, out, N, 1);
}